// Round 7
// baseline (171.353 us; speedup 1.0000x reference)
//
#include <hip/hip_runtime.h>
#include <hip/hip_bf16.h>
#include <stdint.h>

#define BDIM 4096
#define DDIM 1024
#define KSEL 1024
#define MARGINF 0.5f
#define EPSF 1e-6f
#define NT 16  // K-tiles of 64

typedef __attribute__((ext_vector_type(8))) short short8v;
typedef __attribute__((ext_vector_type(4))) float float4v;

// ---------------- helpers ----------------

__device__ __forceinline__ unsigned short f2bf(float f) {
  uint32_t u = __float_as_uint(f);
  uint32_t r = (u + 0x7FFFu + ((u >> 16) & 1u)) >> 16;
  return (unsigned short)r;
}

__device__ __forceinline__ float bf2f(unsigned short u) {
  return __uint_as_float((uint32_t)u << 16);
}

__device__ __forceinline__ void gload_lds16(const void* g, void* l) {
  __builtin_amdgcn_global_load_lds(
      (const __attribute__((address_space(1))) void*)g,
      (__attribute__((address_space(3))) void*)l, 16, 0, 0);
}

// ---------------- prep: fp32 -> bf16, norms, and exact-pipeline posv ------
__global__ __launch_bounds__(256) void prep_kernel(
    const float* __restrict__ x, const float* __restrict__ y,
    unsigned short* __restrict__ xbf, unsigned short* __restrict__ ybf,
    float* __restrict__ xn, float* __restrict__ yn,
    float* __restrict__ posv) {
  int wv = threadIdx.x >> 6, lane = threadIdx.x & 63;
  int row = blockIdx.x * 4 + wv;  // 0..4095
  const float* xp = x + (size_t)row * DDIM;
  const float* yp = y + (size_t)row * DDIM;
  unsigned short* xo = xbf + (size_t)row * DDIM;
  unsigned short* yo = ybf + (size_t)row * DDIM;
  float sxx = 0.f, syy = 0.f, sxy = 0.f;
#pragma unroll
  for (int it = 0; it < 4; ++it) {
    int k = it * 256 + lane * 4;
    float4 xv = *reinterpret_cast<const float4*>(xp + k);
    float4 yv = *reinterpret_cast<const float4*>(yp + k);
    xv.x += EPSF; xv.y += EPSF; xv.z += EPSF; xv.w += EPSF;
    sxx += xv.x * xv.x + xv.y * xv.y + xv.z * xv.z + xv.w * xv.w;
    syy += yv.x * yv.x + yv.y * yv.y + yv.z * yv.z + yv.w * yv.w;
    ushort4 xq, yq;
    xq.x = f2bf(xv.x); xq.y = f2bf(xv.y); xq.z = f2bf(xv.z); xq.w = f2bf(xv.w);
    yq.x = f2bf(yv.x); yq.y = f2bf(yv.y); yq.z = f2bf(yv.z); yq.w = f2bf(yv.w);
    sxy += bf2f(xq.x) * bf2f(yq.x) + bf2f(xq.y) * bf2f(yq.y) +
           bf2f(xq.z) * bf2f(yq.z) + bf2f(xq.w) * bf2f(yq.w);
    *reinterpret_cast<ushort4*>(xo + k) = xq;
    *reinterpret_cast<ushort4*>(yo + k) = yq;
  }
#pragma unroll
  for (int off = 32; off > 0; off >>= 1) {
    sxx += __shfl_down(sxx, off);
    syy += __shfl_down(syy, off);
    sxy += __shfl_down(sxy, off);
  }
  if (lane == 0) {
    xn[row] = sxx;
    yn[row] = syy;
    posv[row] = sqrtf(fmaxf(sxx + syy - 2.f * sxy, 0.f));
  }
}

// ---------------- GEMM: 256x256, BK=64, 8 waves, template phase pipeline --
// Phase body: dsload(this phase's frags, PRE-barrier) -> STAGE next-tile half
// -> counted vmcnt -> s_barrier -> setprio MFMA. Ledger (2 loads/STAGE,
// stage order A0,B0,B1,A1): vmcnt(4) at phi0/phi1/phi3, none at phi2; the
// wait at phase p (pre-barrier) drains the half read by phase p+1's dsload
// for ALL waves (wait precedes the shared barrier). Tail tile: 2 -> 0.

#define VMW(N) asm volatile("s_waitcnt vmcnt(" #N ")" ::: "memory")

#define STAGE(srcbase, ldsb)                                          \
  {                                                                   \
    _Pragma("unroll") for (int c = 0; c < 2; ++c) {                   \
      int L = tid + c * 512;                                          \
      int row_ = L >> 3;                                              \
      int ch_ = (L & 7) ^ (row_ & 7);                                 \
      gload_lds16((srcbase) + (size_t)row_ * DDIM + ch_ * 8,          \
                  (ldsb) + ((w * 64 + c * 512) << 3));                \
    }                                                                 \
  }

#define LOADA(qm, d)                                                  \
  {                                                                   \
    _Pragma("unroll") for (int mm = 0; mm < 4; ++mm)                  \
        _Pragma("unroll") for (int ks = 0; ks < 2; ++ks) {            \
      int rh = wr * 64 + mm * 16 + (lane & 15);                       \
      int ch = (ks * 4 + (lane >> 4)) ^ (rh & 7);                     \
      a[mm][ks] = *reinterpret_cast<const short8v*>(                  \
          smem + ((d) * 2 + (qm)) * 8192 + rh * 64 + ch * 8);         \
    }                                                                 \
  }

#define LOADB(dst, qn, d)                                             \
  {                                                                   \
    _Pragma("unroll") for (int nn = 0; nn < 2; ++nn)                  \
        _Pragma("unroll") for (int ks = 0; ks < 2; ++ks) {            \
      int rh = wc * 32 + nn * 16 + (lane & 15);                       \
      int ch = (ks * 4 + (lane >> 4)) ^ (rh & 7);                     \
      dst[nn][ks] = *reinterpret_cast<const short8v*>(                \
          smem + 32768 + ((d) * 2 + (qn)) * 8192 + rh * 64 + ch * 8); \
    }                                                                 \
  }

#define MFMAQ(qm, qn, bsrc)                                           \
  {                                                                   \
    __builtin_amdgcn_s_setprio(1);                                    \
    _Pragma("unroll") for (int mm = 0; mm < 4; ++mm)                  \
        _Pragma("unroll") for (int nn = 0; nn < 2; ++nn)              \
            _Pragma("unroll") for (int ks = 0; ks < 2; ++ks) {        \
      acc[qm][qn][mm][nn] = __builtin_amdgcn_mfma_f32_16x16x32_bf16(  \
          a[mm][ks], bsrc[nn][ks], acc[qm][qn][mm][nn], 0, 0, 0);     \
    }                                                                 \
    __builtin_amdgcn_s_setprio(0);                                    \
  }

#define BAR() __builtin_amdgcn_s_barrier()

__global__ __launch_bounds__(512, 2) void gemm_dist_kernel(
    const unsigned short* __restrict__ Xb, const unsigned short* __restrict__ Yb,
    const float* __restrict__ xn, const float* __restrict__ yn,
    unsigned short* __restrict__ dist, unsigned short* __restrict__ distT) {
  __shared__ unsigned short smem[65536];  // 128 KB

  int tid = threadIdx.x;
  int lane = tid & 63, w = tid >> 6;
  int wr = w >> 2, wc = w & 3;
  // XCD-aware swizzle over 256 blocks (16x16 tile grid), bijective
  int wg = blockIdx.x;
  int swz = (wg & 7) * 32 + (wg >> 3);
  int brow = (swz >> 4) * 256, bcol = (swz & 15) * 256;

  float4v acc[2][2][4][2];
#pragma unroll
  for (int i = 0; i < 2; ++i)
#pragma unroll
    for (int j = 0; j < 2; ++j)
#pragma unroll
      for (int m = 0; m < 4; ++m)
#pragma unroll
        for (int n = 0; n < 2; ++n) acc[i][j][m][n] = (float4v){0.f, 0.f, 0.f, 0.f};

  short8v a[4][2], b0[2][2], b1[2][2];

  // prologue: stage tile 0 (order A0,B0,B1,A1) -> dbuf 0; drain A0,B0
  STAGE(Xb + (size_t)brow * DDIM, smem);
  STAGE(Yb + (size_t)bcol * DDIM, smem + 32768);
  STAGE(Yb + (size_t)(bcol + 128) * DDIM, smem + 32768 + 8192);
  STAGE(Xb + (size_t)(brow + 128) * DDIM, smem + 8192);
  VMW(4);
  BAR();

  for (int t = 0; t < NT - 1; ++t) {
    int d = t & 1, dn = d ^ 1;
    const unsigned short* xsrc = Xb + (size_t)brow * DDIM + (t + 1) * 64;
    const unsigned short* ysrc = Yb + (size_t)bcol * DDIM + (t + 1) * 64;
    // phi0: Q00; stage A0(t+1); wait drains B1(t) for phi1
    LOADA(0, d);
    LOADB(b0, 0, d);
    STAGE(xsrc, smem + (dn * 2) * 8192);
    VMW(4);
    BAR();
    MFMAQ(0, 0, b0);
    // phi1: Q01; stage B0(t+1); wait drains A1(t) for phi2
    LOADB(b1, 1, d);
    STAGE(ysrc, smem + 32768 + (dn * 2) * 8192);
    VMW(4);
    BAR();
    MFMAQ(0, 1, b1);
    // phi2: Q10; stage B1(t+1); no wait (phi3 reads nothing new)
    LOADA(1, d);
    STAGE(ysrc + (size_t)128 * DDIM, smem + 32768 + (dn * 2 + 1) * 8192);
    BAR();
    MFMAQ(1, 0, b0);
    // phi3: Q11; stage A1(t+1); wait drains A0,B0(t+1) for next phi0
    STAGE(xsrc + (size_t)128 * DDIM, smem + (dn * 2 + 1) * 8192);
    VMW(4);
    BAR();
    MFMAQ(1, 1, b1);
  }
  // tail tile t = NT-1 (d = 1): no staging, drain 2 -> 0
  {
    LOADA(0, 1);
    LOADB(b0, 0, 1);
    VMW(2);
    BAR();
    MFMAQ(0, 0, b0);
    LOADB(b1, 1, 1);
    VMW(0);
    BAR();
    MFMAQ(0, 1, b1);
    LOADA(1, 1);
    BAR();
    MFMAQ(1, 0, b0);
    BAR();
    MFMAQ(1, 1, b1);
  }

  // ---- epilogue: stage bf16 tile transposed in LDS, then write both ----
#pragma unroll
  for (int qm = 0; qm < 2; ++qm) {
#pragma unroll
    for (int qn = 0; qn < 2; ++qn) {
#pragma unroll
      for (int mm = 0; mm < 4; ++mm) {
#pragma unroll
        for (int nn = 0; nn < 2; ++nn) {
          int r0 = qm * 128 + wr * 64 + mm * 16 + (lane >> 4) * 4;
          int c = qn * 128 + wc * 32 + nn * 16 + (lane & 15);
          float yv = yn[bcol + c];
          ushort4 st;
          unsigned short* sp = reinterpret_cast<unsigned short*>(&st);
#pragma unroll
          for (int j = 0; j < 4; ++j) {
            float sq = xn[brow + r0 + j] + yv - 2.0f * acc[qm][qn][mm][nn][j];
            sp[j] = f2bf(sqrtf(fmaxf(sq, 0.f)));
          }
          int phys = (r0 >> 3) ^ (c & 31);
          *reinterpret_cast<uint2*>(reinterpret_cast<char*>(smem) + c * 512 +
                                    phys * 16 + (r0 & 7) * 2) =
              *reinterpret_cast<uint2*>(&st);
        }
      }
    }
  }
  __syncthreads();
  // distT: thread -> (col, r-half), 256B contiguous vector stores
  {
    int c = tid >> 1, half = tid & 1;
    unsigned short* gout = distT + (size_t)(bcol + c) * BDIM + brow + half * 128;
#pragma unroll
    for (int i = 0; i < 16; ++i) {
      int rc = half * 16 + i;
      int phys = rc ^ (c & 31);
      uint4 v = *reinterpret_cast<const uint4*>(
          reinterpret_cast<const char*>(smem) + c * 512 + phys * 16);
      *reinterpret_cast<uint4*>(gout + i * 8) = v;
    }
  }
  // dist: thread -> (row, c-half), scalar LDS gather + 256B vector stores
  {
    int r = tid >> 1, half = tid & 1;
    alignas(16) unsigned short buf[128];
#pragma unroll
    for (int i = 0; i < 128; ++i) {
      int c = half * 128 + i;
      int phys = (r >> 3) ^ (c & 31);
      buf[i] = smem[c * 256 + phys * 8 + (r & 7)];
    }
    unsigned short* gout = dist + (size_t)(brow + r) * BDIM + bcol + half * 128;
    const uint4* b4 = reinterpret_cast<const uint4*>(buf);
#pragma unroll
    for (int j = 0; j < 16; ++j)
      *reinterpret_cast<uint4*>(gout + j * 8) = b4[j];
  }
}

// ---------------- per-row exact top-K-smallest hinge sum (bf16 keys) ------
__global__ __launch_bounds__(256, 4) void select_kernel(
    const unsigned short* __restrict__ dist,
    const unsigned short* __restrict__ distT,
    const float* __restrict__ posv,
    float* __restrict__ rxy, float* __restrict__ ryx) {
  int lane = threadIdx.x & 63, w = threadIdx.x >> 6;
  int r = blockIdx.x * 4 + w;           // 0..8191
  int rr = (r < BDIM) ? r : r - BDIM;
  const unsigned short* rowp =
      ((r < BDIM) ? dist : distT) + (size_t)rr * BDIM;
  float pos = posv[rr];

  uint32_t key[64];
  uint32_t kmin = 0xFFFFu, kmax = 0u;
#pragma unroll
  for (int i = 0; i < 8; ++i) {
    int idx0 = i * 512 + lane * 8;
    uint4 v = *reinterpret_cast<const uint4*>(rowp + idx0);
    uint32_t pk[4] = {v.x, v.y, v.z, v.w};
#pragma unroll
    for (int p = 0; p < 4; ++p) {
      uint32_t lo = pk[p] & 0xFFFFu, hi = pk[p] >> 16;
      kmin = min(kmin, min(lo, hi));
      kmax = max(kmax, max(lo, hi));
      int idx = idx0 + p * 2;
      key[i * 8 + p * 2 + 0] = (idx + 0 == rr) ? 0xFFFFu : lo;
      key[i * 8 + p * 2 + 1] = (idx + 1 == rr) ? 0xFFFFu : hi;
    }
  }
#pragma unroll
  for (int off = 32; off > 0; off >>= 1) {
    kmin = min(kmin, (uint32_t)__shfl_xor((int)kmin, off));
    kmax = max(kmax, (uint32_t)__shfl_xor((int)kmax, off));
  }

  uint32_t a = kmin, b = kmax;
  uint32_t T;
  bool found = false;
  while (a < b) {
    uint32_t m = (a + b) >> 1;
    int c = 0;
#pragma unroll
    for (int i = 0; i < 64; ++i) c += __popcll(__ballot(key[i] <= m));
    if (c == KSEL) { T = m; found = true; break; }
    if (c > KSEL) b = m; else a = m + 1;
  }
  if (!found) T = a;

  float Tf = __uint_as_float(T << 16);
  float pm = MARGINF + pos;
  float local = 0.f;
  int cnt_less = 0;
#pragma unroll
  for (int i = 0; i < 64; ++i) {
    uint32_t k = key[i];
    cnt_less += __popcll(__ballot(k < T));
    float d = __uint_as_float(k << 16);
    local += (k < T) ? fmaxf(pm - d, 0.f) : 0.f;
  }
#pragma unroll
  for (int off = 32; off > 0; off >>= 1) local += __shfl_xor(local, off);
  if (lane == 0) {
    float loss = local + (float)(KSEL - cnt_less) * fmaxf(pm - Tf, 0.f);
    if (r < BDIM) rxy[rr] = loss; else ryx[rr] = loss;
  }
}

// ---------------- final reduction ----------------
__global__ void finalize_kernel(const float* __restrict__ rxy,
                                const float* __restrict__ ryx,
                                float* __restrict__ out) {
  const float* src = (blockIdx.x == 0) ? rxy : ryx;
  int tid = threadIdx.x;
  double local = 0.0;
  for (int i = tid; i < BDIM; i += 256) local += (double)src[i];
  int lane = tid & 63, w = tid >> 6;
#pragma unroll
  for (int off = 32; off > 0; off >>= 1) local += __shfl_down(local, off);
  __shared__ double wsd[4];
  if (lane == 0) wsd[w] = local;
  __syncthreads();
  if (tid == 0) {
    double s = wsd[0] + wsd[1] + wsd[2] + wsd[3];
    out[blockIdx.x] = (float)(s / ((double)BDIM * (double)KSEL));
  }
}

// ---------------- launch ----------------
extern "C" void kernel_launch(void* const* d_in, const int* in_sizes, int n_in,
                              void* d_out, int out_size, void* d_ws,
                              size_t ws_size, hipStream_t stream) {
  const float* x = (const float*)d_in[0];
  const float* y = (const float*)d_in[1];
  float* out = (float*)d_out;

  char* ws = (char*)d_ws;
  size_t o = 0;
  auto take = [&](size_t bytes) -> void* {
    void* p = (void*)(ws + o);
    o += (bytes + 255) & ~(size_t)255;
    return p;
  };
  unsigned short* xbf = (unsigned short*)take((size_t)BDIM * DDIM * 2);
  unsigned short* ybf = (unsigned short*)take((size_t)BDIM * DDIM * 2);
  float* xn = (float*)take((size_t)BDIM * 4);
  float* yn = (float*)take((size_t)BDIM * 4);
  float* rxy = (float*)take((size_t)BDIM * 4);
  float* ryx = (float*)take((size_t)BDIM * 4);
  float* posv = (float*)take((size_t)BDIM * 4);
  unsigned short* dist = (unsigned short*)take((size_t)BDIM * BDIM * 2);
  unsigned short* distT = (unsigned short*)take((size_t)BDIM * BDIM * 2);

  prep_kernel<<<BDIM / 4, 256, 0, stream>>>(x, y, xbf, ybf, xn, yn, posv);
  gemm_dist_kernel<<<256, 512, 0, stream>>>(xbf, ybf, xn, yn, dist, distT);
  select_kernel<<<2 * BDIM / 4, 256, 0, stream>>>(dist, distT, posv, rxy, ryx);
  finalize_kernel<<<2, 256, 0, stream>>>(rxy, ryx, out);
}

// Round 8
// 166.335 us; speedup vs baseline: 1.0302x; 1.0302x over previous
//
#include <hip/hip_runtime.h>
#include <hip/hip_bf16.h>
#include <stdint.h>

#define BDIM 4096
#define DDIM 1024
#define KSEL 1024
#define MARGINF 0.5f
#define EPSF 1e-6f
#define NT 16  // K-tiles of 64

typedef __attribute__((ext_vector_type(8))) short short8v;
typedef __attribute__((ext_vector_type(4))) float float4v;

// ---------------- helpers ----------------

__device__ __forceinline__ unsigned short f2bf(float f) {
  uint32_t u = __float_as_uint(f);
  uint32_t r = (u + 0x7FFFu + ((u >> 16) & 1u)) >> 16;
  return (unsigned short)r;
}

__device__ __forceinline__ float bf2f(unsigned short u) {
  return __uint_as_float((uint32_t)u << 16);
}

__device__ __forceinline__ void gload_lds16(const void* g, void* l) {
  __builtin_amdgcn_global_load_lds(
      (const __attribute__((address_space(1))) void*)g,
      (__attribute__((address_space(3))) void*)l, 16, 0, 0);
}

// ---------------- prep: fp32 -> bf16, norms, and exact-pipeline posv ------
__global__ __launch_bounds__(256) void prep_kernel(
    const float* __restrict__ x, const float* __restrict__ y,
    unsigned short* __restrict__ xbf, unsigned short* __restrict__ ybf,
    float* __restrict__ xn, float* __restrict__ yn,
    float* __restrict__ posv) {
  int wv = threadIdx.x >> 6, lane = threadIdx.x & 63;
  int row = blockIdx.x * 4 + wv;  // 0..4095
  const float* xp = x + (size_t)row * DDIM;
  const float* yp = y + (size_t)row * DDIM;
  unsigned short* xo = xbf + (size_t)row * DDIM;
  unsigned short* yo = ybf + (size_t)row * DDIM;
  float sxx = 0.f, syy = 0.f, sxy = 0.f;
#pragma unroll
  for (int it = 0; it < 4; ++it) {
    int k = it * 256 + lane * 4;
    float4 xv = *reinterpret_cast<const float4*>(xp + k);
    float4 yv = *reinterpret_cast<const float4*>(yp + k);
    xv.x += EPSF; xv.y += EPSF; xv.z += EPSF; xv.w += EPSF;
    sxx += xv.x * xv.x + xv.y * xv.y + xv.z * xv.z + xv.w * xv.w;
    syy += yv.x * yv.x + yv.y * yv.y + yv.z * yv.z + yv.w * yv.w;
    ushort4 xq, yq;
    xq.x = f2bf(xv.x); xq.y = f2bf(xv.y); xq.z = f2bf(xv.z); xq.w = f2bf(xv.w);
    yq.x = f2bf(yv.x); yq.y = f2bf(yv.y); yq.z = f2bf(yv.z); yq.w = f2bf(yv.w);
    sxy += bf2f(xq.x) * bf2f(yq.x) + bf2f(xq.y) * bf2f(yq.y) +
           bf2f(xq.z) * bf2f(yq.z) + bf2f(xq.w) * bf2f(yq.w);
    *reinterpret_cast<ushort4*>(xo + k) = xq;
    *reinterpret_cast<ushort4*>(yo + k) = yq;
  }
#pragma unroll
  for (int off = 32; off > 0; off >>= 1) {
    sxx += __shfl_down(sxx, off);
    syy += __shfl_down(syy, off);
    sxy += __shfl_down(sxy, off);
  }
  if (lane == 0) {
    xn[row] = sxx;
    yn[row] = syy;
    posv[row] = sqrtf(fmaxf(sxx + syy - 2.f * sxy, 0.f));
  }
}

// ---------------- GEMM: 256x256, BK=64, 8 waves, template phase pipeline --
// Main loop unchanged from round 6 (verified correct). Epilogue rewritten:
// instruction-level full-line global stores — per store instruction, lanes
// 0-31 cover one column/row's contiguous 512B (no reliance on L2 write
// combining across instructions).

#define VMW(N) asm volatile("s_waitcnt vmcnt(" #N ")" ::: "memory")

#define STAGE(srcbase, ldsb)                                          \
  {                                                                   \
    _Pragma("unroll") for (int c = 0; c < 2; ++c) {                   \
      int L = tid + c * 512;                                          \
      int row_ = L >> 3;                                              \
      int ch_ = (L & 7) ^ (row_ & 7);                                 \
      gload_lds16((srcbase) + (size_t)row_ * DDIM + ch_ * 8,          \
                  (ldsb) + ((w * 64 + c * 512) << 3));                \
    }                                                                 \
  }

#define LOADA(qm, d)                                                  \
  {                                                                   \
    _Pragma("unroll") for (int mm = 0; mm < 4; ++mm)                  \
        _Pragma("unroll") for (int ks = 0; ks < 2; ++ks) {            \
      int rh = wr * 64 + mm * 16 + (lane & 15);                       \
      int ch = (ks * 4 + (lane >> 4)) ^ (rh & 7);                     \
      a[mm][ks] = *reinterpret_cast<const short8v*>(                  \
          smem + ((d) * 2 + (qm)) * 8192 + rh * 64 + ch * 8);         \
    }                                                                 \
  }

#define LOADB(dst, qn, d)                                             \
  {                                                                   \
    _Pragma("unroll") for (int nn = 0; nn < 2; ++nn)                  \
        _Pragma("unroll") for (int ks = 0; ks < 2; ++ks) {            \
      int rh = wc * 32 + nn * 16 + (lane & 15);                       \
      int ch = (ks * 4 + (lane >> 4)) ^ (rh & 7);                     \
      dst[nn][ks] = *reinterpret_cast<const short8v*>(                \
          smem + 32768 + ((d) * 2 + (qn)) * 8192 + rh * 64 + ch * 8); \
    }                                                                 \
  }

#define MFMAQ(qm, qn, bsrc)                                           \
  {                                                                   \
    __builtin_amdgcn_s_setprio(1);                                    \
    _Pragma("unroll") for (int mm = 0; mm < 4; ++mm)                  \
        _Pragma("unroll") for (int nn = 0; nn < 2; ++nn)              \
            _Pragma("unroll") for (int ks = 0; ks < 2; ++ks) {        \
      acc[qm][qn][mm][nn] = __builtin_amdgcn_mfma_f32_16x16x32_bf16(  \
          a[mm][ks], bsrc[nn][ks], acc[qm][qn][mm][nn], 0, 0, 0);     \
    }                                                                 \
    __builtin_amdgcn_s_setprio(0);                                    \
  }

#define BAR() __builtin_amdgcn_s_barrier()

__global__ __launch_bounds__(512, 2) void gemm_dist_kernel(
    const unsigned short* __restrict__ Xb, const unsigned short* __restrict__ Yb,
    const float* __restrict__ xn, const float* __restrict__ yn,
    unsigned short* __restrict__ dist, unsigned short* __restrict__ distT) {
  __shared__ unsigned short smem[65536];  // 128 KB

  int tid = threadIdx.x;
  int lane = tid & 63, w = tid >> 6;
  int wr = w >> 2, wc = w & 3;
  // XCD-aware swizzle over 256 blocks (16x16 tile grid), bijective
  int wg = blockIdx.x;
  int swz = (wg & 7) * 32 + (wg >> 3);
  int brow = (swz >> 4) * 256, bcol = (swz & 15) * 256;

  float4v acc[2][2][4][2];
#pragma unroll
  for (int i = 0; i < 2; ++i)
#pragma unroll
    for (int j = 0; j < 2; ++j)
#pragma unroll
      for (int m = 0; m < 4; ++m)
#pragma unroll
        for (int n = 0; n < 2; ++n) acc[i][j][m][n] = (float4v){0.f, 0.f, 0.f, 0.f};

  short8v a[4][2], b0[2][2], b1[2][2];

  // prologue: stage tile 0 (order A0,B0,B1,A1) -> dbuf 0; drain A0,B0
  STAGE(Xb + (size_t)brow * DDIM, smem);
  STAGE(Yb + (size_t)bcol * DDIM, smem + 32768);
  STAGE(Yb + (size_t)(bcol + 128) * DDIM, smem + 32768 + 8192);
  STAGE(Xb + (size_t)(brow + 128) * DDIM, smem + 8192);
  VMW(4);
  BAR();

  for (int t = 0; t < NT - 1; ++t) {
    int d = t & 1, dn = d ^ 1;
    const unsigned short* xsrc = Xb + (size_t)brow * DDIM + (t + 1) * 64;
    const unsigned short* ysrc = Yb + (size_t)bcol * DDIM + (t + 1) * 64;
    // phi0: Q00; stage A0(t+1)
    LOADA(0, d);
    LOADB(b0, 0, d);
    STAGE(xsrc, smem + (dn * 2) * 8192);
    VMW(4);
    BAR();
    MFMAQ(0, 0, b0);
    // phi1: Q01; stage B0(t+1)
    LOADB(b1, 1, d);
    STAGE(ysrc, smem + 32768 + (dn * 2) * 8192);
    VMW(4);
    BAR();
    MFMAQ(0, 1, b1);
    // phi2: Q10; stage B1(t+1); no wait
    LOADA(1, d);
    STAGE(ysrc + (size_t)128 * DDIM, smem + 32768 + (dn * 2 + 1) * 8192);
    BAR();
    MFMAQ(1, 0, b0);
    // phi3: Q11; stage A1(t+1)
    STAGE(xsrc + (size_t)128 * DDIM, smem + (dn * 2 + 1) * 8192);
    VMW(4);
    BAR();
    MFMAQ(1, 1, b1);
  }
  // tail tile t = NT-1 (d = 1): no staging, drain 2 -> 0
  {
    LOADA(0, 1);
    LOADB(b0, 0, 1);
    VMW(2);
    BAR();
    MFMAQ(0, 0, b0);
    LOADB(b1, 1, 1);
    VMW(0);
    BAR();
    MFMAQ(0, 1, b1);
    LOADA(1, 1);
    BAR();
    MFMAQ(1, 0, b0);
    BAR();
    MFMAQ(1, 1, b1);
  }

  __syncthreads();

  // ---- epilogue ----
  // LDS transposed tile, swizzled: byte(c,r) = c*512 + (2r ^ ((c&31)<<4)).
  // K=(c&31)<<4 is a multiple of 16, so 16B-chunk reads stay contiguous and
  // map back to contiguous logical rows.
  char* sbytes = reinterpret_cast<char*>(smem);
#pragma unroll
  for (int qm = 0; qm < 2; ++qm) {
#pragma unroll
    for (int qn = 0; qn < 2; ++qn) {
#pragma unroll
      for (int mm = 0; mm < 4; ++mm) {
#pragma unroll
        for (int nn = 0; nn < 2; ++nn) {
          int r0 = qm * 128 + wr * 64 + mm * 16 + (lane >> 4) * 4;
          int c = qn * 128 + wc * 32 + nn * 16 + (lane & 15);
          float yv = yn[bcol + c];
          ushort4 st;
          unsigned short* sp = reinterpret_cast<unsigned short*>(&st);
#pragma unroll
          for (int j = 0; j < 4; ++j) {
            float sq = xn[brow + r0 + j] + yv - 2.0f * acc[qm][qn][mm][nn][j];
            sp[j] = f2bf(sqrtf(fmaxf(sq, 0.f)));
          }
          *reinterpret_cast<uint2*>(sbytes + c * 512 +
                                    ((r0 * 2) ^ ((c & 31) << 4))) =
              *reinterpret_cast<uint2*>(&st);
        }
      }
    }
  }
  __syncthreads();
  // distT: per instruction, lanes 0-31 cover column c's full 512B (16 full
  // 64B lines per wave-instruction). 2 columns per instruction per wave.
  {
    int chunk = lane & 31, cs = lane >> 5;
#pragma unroll
    for (int i = 0; i < 16; ++i) {
      int c = w * 32 + i * 2 + cs;
      uint4 v = *reinterpret_cast<const uint4*>(
          sbytes + c * 512 + ((chunk * 16) ^ ((c & 31) << 4)));
      *reinterpret_cast<uint4*>(distT + (size_t)(bcol + c) * BDIM + brow +
                                chunk * 8) = v;
    }
  }
  // dist: per instruction, lanes 0-31 cover row r's full 512B; scalar LDS
  // gather (8 u16 per 16B chunk), full-line stores.
  {
    int chunk = lane & 31, rs = lane >> 5;
#pragma unroll
    for (int i = 0; i < 16; ++i) {
      int r = w * 32 + i * 2 + rs;
      alignas(16) unsigned short buf[8];
#pragma unroll
      for (int j = 0; j < 8; ++j) {
        int c = chunk * 8 + j;
        buf[j] = *reinterpret_cast<const unsigned short*>(
            sbytes + c * 512 + ((r * 2) ^ ((c & 31) << 4)));
      }
      *reinterpret_cast<uint4*>(dist + (size_t)(brow + r) * BDIM + bcol +
                                chunk * 8) = *reinterpret_cast<const uint4*>(buf);
    }
  }
}

// ---------------- per-row exact top-K-smallest hinge sum (bf16 keys) ------
__global__ __launch_bounds__(256, 4) void select_kernel(
    const unsigned short* __restrict__ dist,
    const unsigned short* __restrict__ distT,
    const float* __restrict__ posv,
    float* __restrict__ rxy, float* __restrict__ ryx) {
  int lane = threadIdx.x & 63, w = threadIdx.x >> 6;
  int r = blockIdx.x * 4 + w;           // 0..8191
  int rr = (r < BDIM) ? r : r - BDIM;
  const unsigned short* rowp =
      ((r < BDIM) ? dist : distT) + (size_t)rr * BDIM;
  float pos = posv[rr];

  uint32_t key[64];
  uint32_t kmin = 0xFFFFu, kmax = 0u;
#pragma unroll
  for (int i = 0; i < 8; ++i) {
    int idx0 = i * 512 + lane * 8;
    uint4 v = *reinterpret_cast<const uint4*>(rowp + idx0);
    uint32_t pk[4] = {v.x, v.y, v.z, v.w};
#pragma unroll
    for (int p = 0; p < 4; ++p) {
      uint32_t lo = pk[p] & 0xFFFFu, hi = pk[p] >> 16;
      kmin = min(kmin, min(lo, hi));
      kmax = max(kmax, max(lo, hi));
      int idx = idx0 + p * 2;
      key[i * 8 + p * 2 + 0] = (idx + 0 == rr) ? 0xFFFFu : lo;
      key[i * 8 + p * 2 + 1] = (idx + 1 == rr) ? 0xFFFFu : hi;
    }
  }
#pragma unroll
  for (int off = 32; off > 0; off >>= 1) {
    kmin = min(kmin, (uint32_t)__shfl_xor((int)kmin, off));
    kmax = max(kmax, (uint32_t)__shfl_xor((int)kmax, off));
  }

  uint32_t a = kmin, b = kmax;
  uint32_t T;
  bool found = false;
  while (a < b) {
    uint32_t m = (a + b) >> 1;
    int c = 0;
#pragma unroll
    for (int i = 0; i < 64; ++i) c += __popcll(__ballot(key[i] <= m));
    if (c == KSEL) { T = m; found = true; break; }
    if (c > KSEL) b = m; else a = m + 1;
  }
  if (!found) T = a;

  float Tf = __uint_as_float(T << 16);
  float pm = MARGINF + pos;
  float local = 0.f;
  int cnt_less = 0;
#pragma unroll
  for (int i = 0; i < 64; ++i) {
    uint32_t k = key[i];
    cnt_less += __popcll(__ballot(k < T));
    float d = __uint_as_float(k << 16);
    local += (k < T) ? fmaxf(pm - d, 0.f) : 0.f;
  }
#pragma unroll
  for (int off = 32; off > 0; off >>= 1) local += __shfl_xor(local, off);
  if (lane == 0) {
    float loss = local + (float)(KSEL - cnt_less) * fmaxf(pm - Tf, 0.f);
    if (r < BDIM) rxy[rr] = loss; else ryx[rr] = loss;
  }
}

// ---------------- final reduction ----------------
__global__ void finalize_kernel(const float* __restrict__ rxy,
                                const float* __restrict__ ryx,
                                float* __restrict__ out) {
  const float* src = (blockIdx.x == 0) ? rxy : ryx;
  int tid = threadIdx.x;
  double local = 0.0;
  for (int i = tid; i < BDIM; i += 256) local += (double)src[i];
  int lane = tid & 63, w = tid >> 6;
#pragma unroll
  for (int off = 32; off > 0; off >>= 1) local += __shfl_down(local, off);
  __shared__ double wsd[4];
  if (lane == 0) wsd[w] = local;
  __syncthreads();
  if (tid == 0) {
    double s = wsd[0] + wsd[1] + wsd[2] + wsd[3];
    out[blockIdx.x] = (float)(s / ((double)BDIM * (double)KSEL));
  }
}

// ---------------- launch ----------------
extern "C" void kernel_launch(void* const* d_in, const int* in_sizes, int n_in,
                              void* d_out, int out_size, void* d_ws,
                              size_t ws_size, hipStream_t stream) {
  const float* x = (const float*)d_in[0];
  const float* y = (const float*)d_in[1];
  float* out = (float*)d_out;

  char* ws = (char*)d_ws;
  size_t o = 0;
  auto take = [&](size_t bytes) -> void* {
    void* p = (void*)(ws + o);
    o += (bytes + 255) & ~(size_t)255;
    return p;
  };
  unsigned short* xbf = (unsigned short*)take((size_t)BDIM * DDIM * 2);
  unsigned short* ybf = (unsigned short*)take((size_t)BDIM * DDIM * 2);
  float* xn = (float*)take((size_t)BDIM * 4);
  float* yn = (float*)take((size_t)BDIM * 4);
  float* rxy = (float*)take((size_t)BDIM * 4);
  float* ryx = (float*)take((size_t)BDIM * 4);
  float* posv = (float*)take((size_t)BDIM * 4);
  unsigned short* dist = (unsigned short*)take((size_t)BDIM * BDIM * 2);
  unsigned short* distT = (unsigned short*)take((size_t)BDIM * BDIM * 2);

  prep_kernel<<<BDIM / 4, 256, 0, stream>>>(x, y, xbf, ybf, xn, yn, posv);
  gemm_dist_kernel<<<256, 512, 0, stream>>>(xbf, ybf, xn, yn, dist, distT);
  select_kernel<<<2 * BDIM / 4, 256, 0, stream>>>(dist, distT, posv, rxy, ryx);
  finalize_kernel<<<2, 256, 0, stream>>>(rxy, ryx, out);
}

// Round 9
// 148.157 us; speedup vs baseline: 1.1566x; 1.1227x over previous
//
#include <hip/hip_runtime.h>
#include <hip/hip_bf16.h>
#include <stdint.h>

#define BDIM 4096
#define DDIM 1024
#define KSEL 1024
#define MARGINF 0.5f
#define EPSF 1e-6f
#define NT 16  // K-tiles of 64

typedef __attribute__((ext_vector_type(8))) short short8v;
typedef __attribute__((ext_vector_type(4))) float float4v;

// ---------------- helpers ----------------

__device__ __forceinline__ unsigned short f2bf(float f) {
  uint32_t u = __float_as_uint(f);
  uint32_t r = (u + 0x7FFFu + ((u >> 16) & 1u)) >> 16;
  return (unsigned short)r;
}

__device__ __forceinline__ float bf2f(unsigned short u) {
  return __uint_as_float((uint32_t)u << 16);
}

__device__ __forceinline__ void gload_lds16(const void* g, void* l) {
  __builtin_amdgcn_global_load_lds(
      (const __attribute__((address_space(1))) void*)g,
      (__attribute__((address_space(3))) void*)l, 16, 0, 0);
}

// ---------------- prep: fp32 -> bf16, norms, and exact-pipeline posv ------
__global__ __launch_bounds__(256) void prep_kernel(
    const float* __restrict__ x, const float* __restrict__ y,
    unsigned short* __restrict__ xbf, unsigned short* __restrict__ ybf,
    float* __restrict__ xn, float* __restrict__ yn,
    float* __restrict__ posv) {
  int wv = threadIdx.x >> 6, lane = threadIdx.x & 63;
  int row = blockIdx.x * 4 + wv;  // 0..4095
  const float* xp = x + (size_t)row * DDIM;
  const float* yp = y + (size_t)row * DDIM;
  unsigned short* xo = xbf + (size_t)row * DDIM;
  unsigned short* yo = ybf + (size_t)row * DDIM;
  float sxx = 0.f, syy = 0.f, sxy = 0.f;
#pragma unroll
  for (int it = 0; it < 4; ++it) {
    int k = it * 256 + lane * 4;
    float4 xv = *reinterpret_cast<const float4*>(xp + k);
    float4 yv = *reinterpret_cast<const float4*>(yp + k);
    xv.x += EPSF; xv.y += EPSF; xv.z += EPSF; xv.w += EPSF;
    sxx += xv.x * xv.x + xv.y * xv.y + xv.z * xv.z + xv.w * xv.w;
    syy += yv.x * yv.x + yv.y * yv.y + yv.z * yv.z + yv.w * yv.w;
    ushort4 xq, yq;
    xq.x = f2bf(xv.x); xq.y = f2bf(xv.y); xq.z = f2bf(xv.z); xq.w = f2bf(xv.w);
    yq.x = f2bf(yv.x); yq.y = f2bf(yv.y); yq.z = f2bf(yv.z); yq.w = f2bf(yv.w);
    sxy += bf2f(xq.x) * bf2f(yq.x) + bf2f(xq.y) * bf2f(yq.y) +
           bf2f(xq.z) * bf2f(yq.z) + bf2f(xq.w) * bf2f(yq.w);
    *reinterpret_cast<ushort4*>(xo + k) = xq;
    *reinterpret_cast<ushort4*>(yo + k) = yq;
  }
#pragma unroll
  for (int off = 32; off > 0; off >>= 1) {
    sxx += __shfl_down(sxx, off);
    syy += __shfl_down(syy, off);
    sxy += __shfl_down(sxy, off);
  }
  if (lane == 0) {
    xn[row] = sxx;
    yn[row] = syy;
    posv[row] = sqrtf(fmaxf(sxx + syy - 2.f * sxy, 0.f));
  }
}

// ---------------- GEMM: 256x256, BK=64, 8 waves, 1 barrier per K-tile -----
// Per tile: stage t+1 (8 gloads) -> 24 ds_read_b128 (all frags) -> 64 MFMA
// cluster -> vmcnt(0) (cheap: issued ~700cyc earlier) -> s_barrier. Double
// buffer makes 1 barrier/tile sufficient; waves drift out of lockstep so
// LDS and MFMA pipes overlap across waves.

#define VMW(N) asm volatile("s_waitcnt vmcnt(" #N ")" ::: "memory")

#define STAGE(srcbase, ldsb)                                          \
  {                                                                   \
    _Pragma("unroll") for (int c = 0; c < 2; ++c) {                   \
      int L = tid + c * 512;                                          \
      int row_ = L >> 3;                                              \
      int ch_ = (L & 7) ^ (row_ & 7);                                 \
      gload_lds16((srcbase) + (size_t)row_ * DDIM + ch_ * 8,          \
                  (ldsb) + ((w * 64 + c * 512) << 3));                \
    }                                                                 \
  }

#define LOADA(dst, qm, d)                                             \
  {                                                                   \
    _Pragma("unroll") for (int mm = 0; mm < 4; ++mm)                  \
        _Pragma("unroll") for (int ks = 0; ks < 2; ++ks) {            \
      int rh = wr * 64 + mm * 16 + (lane & 15);                       \
      int ch = (ks * 4 + (lane >> 4)) ^ (rh & 7);                     \
      dst[mm][ks] = *reinterpret_cast<const short8v*>(                \
          smem + ((d) * 2 + (qm)) * 8192 + rh * 64 + ch * 8);         \
    }                                                                 \
  }

#define LOADB(dst, qn, d)                                             \
  {                                                                   \
    _Pragma("unroll") for (int nn = 0; nn < 2; ++nn)                  \
        _Pragma("unroll") for (int ks = 0; ks < 2; ++ks) {            \
      int rh = wc * 32 + nn * 16 + (lane & 15);                       \
      int ch = (ks * 4 + (lane >> 4)) ^ (rh & 7);                     \
      dst[nn][ks] = *reinterpret_cast<const short8v*>(                \
          smem + 32768 + ((d) * 2 + (qn)) * 8192 + rh * 64 + ch * 8); \
    }                                                                 \
  }

#define BAR() __builtin_amdgcn_s_barrier()

__global__ __launch_bounds__(512, 2) void gemm_dist_kernel(
    const unsigned short* __restrict__ Xb, const unsigned short* __restrict__ Yb,
    const float* __restrict__ xn, const float* __restrict__ yn,
    unsigned short* __restrict__ dist, unsigned short* __restrict__ distT) {
  __shared__ unsigned short smem[65536];  // 128 KB

  int tid = threadIdx.x;
  int lane = tid & 63, w = tid >> 6;
  int wr = w >> 2, wc = w & 3;
  // XCD-aware swizzle over 256 blocks (16x16 tile grid), bijective
  int wg = blockIdx.x;
  int swz = (wg & 7) * 32 + (wg >> 3);
  int brow = (swz >> 4) * 256, bcol = (swz & 15) * 256;

  float4v acc[2][2][4][2];
#pragma unroll
  for (int i = 0; i < 2; ++i)
#pragma unroll
    for (int j = 0; j < 2; ++j)
#pragma unroll
      for (int m = 0; m < 4; ++m)
#pragma unroll
        for (int n = 0; n < 2; ++n) acc[i][j][m][n] = (float4v){0.f, 0.f, 0.f, 0.f};

  short8v a0[4][2], a1[4][2], b0[2][2], b1[2][2];

  // prologue: stage tile 0 -> dbuf 0; full drain once
  STAGE(Xb + (size_t)brow * DDIM, smem);
  STAGE(Xb + (size_t)(brow + 128) * DDIM, smem + 8192);
  STAGE(Yb + (size_t)bcol * DDIM, smem + 32768);
  STAGE(Yb + (size_t)(bcol + 128) * DDIM, smem + 32768 + 8192);
  VMW(0);
  BAR();

  for (int t = 0; t < NT; ++t) {
    int d = t & 1, dn = d ^ 1;
    // stage tile t+1 into the other buffer (8 gloads, land under the MFMAs)
    if (t < NT - 1) {
      const unsigned short* xsrc = Xb + (size_t)brow * DDIM + (t + 1) * 64;
      const unsigned short* ysrc = Yb + (size_t)bcol * DDIM + (t + 1) * 64;
      STAGE(xsrc, smem + (dn * 2) * 8192);
      STAGE(xsrc + (size_t)128 * DDIM, smem + (dn * 2 + 1) * 8192);
      STAGE(ysrc, smem + 32768 + (dn * 2) * 8192);
      STAGE(ysrc + (size_t)128 * DDIM, smem + 32768 + (dn * 2 + 1) * 8192);
    }
    // read all fragments for tile t (24 ds_read_b128)
    LOADA(a0, 0, d);
    LOADB(b0, 0, d);
    LOADA(a1, 1, d);
    LOADB(b1, 1, d);
    // full 64-MFMA cluster
    __builtin_amdgcn_s_setprio(1);
#pragma unroll
    for (int qn = 0; qn < 2; ++qn)
#pragma unroll
      for (int mm = 0; mm < 4; ++mm)
#pragma unroll
        for (int nn = 0; nn < 2; ++nn)
#pragma unroll
          for (int ks = 0; ks < 2; ++ks) {
            acc[0][qn][mm][nn] = __builtin_amdgcn_mfma_f32_16x16x32_bf16(
                a0[mm][ks], (qn ? b1 : b0)[nn][ks], acc[0][qn][mm][nn], 0, 0, 0);
            acc[1][qn][mm][nn] = __builtin_amdgcn_mfma_f32_16x16x32_bf16(
                a1[mm][ks], (qn ? b1 : b0)[nn][ks], acc[1][qn][mm][nn], 0, 0, 0);
          }
    __builtin_amdgcn_s_setprio(0);
    // ensure staged writes landed (per-wave), then collective barrier
    VMW(0);
    BAR();
  }

  // ---- epilogue ----
  // Column-major LDS tile: byte(c,r) = c*512 + ((2r) ^ (m1(c)<<4)),
  // m1(c) = (c&7)^((c>>3)&7). Multiple-of-16 mask keeps 16B distT chunks
  // contiguous and 8B acc-writes aligned; m1 varies with c>>3 so the dist
  // row-gather (c stepping by 8 across lanes) spreads over 8 banks (4-way).
  char* sbytes = reinterpret_cast<char*>(smem);
#pragma unroll
  for (int qm = 0; qm < 2; ++qm) {
#pragma unroll
    for (int qn = 0; qn < 2; ++qn) {
#pragma unroll
      for (int mm = 0; mm < 4; ++mm) {
#pragma unroll
        for (int nn = 0; nn < 2; ++nn) {
          int r0 = qm * 128 + wr * 64 + mm * 16 + (lane >> 4) * 4;
          int c = qn * 128 + wc * 32 + nn * 16 + (lane & 15);
          float yv = yn[bcol + c];
          ushort4 st;
          unsigned short* sp = reinterpret_cast<unsigned short*>(&st);
#pragma unroll
          for (int j = 0; j < 4; ++j) {
            float sq = xn[brow + r0 + j] + yv - 2.0f * acc[qm][qn][mm][nn][j];
            sp[j] = f2bf(sqrtf(fmaxf(sq, 0.f)));
          }
          int m1 = (c & 7) ^ ((c >> 3) & 7);
          *reinterpret_cast<uint2*>(sbytes + c * 512 +
                                    ((r0 * 2) ^ (m1 << 4))) =
              *reinterpret_cast<uint2*>(&st);
        }
      }
    }
  }
  __syncthreads();
  // distT: lanes 0-31 cover column c's full 512B per instruction
  {
    int chunk = lane & 31, cs = lane >> 5;
#pragma unroll
    for (int i = 0; i < 16; ++i) {
      int c = w * 32 + i * 2 + cs;
      int m1 = (c & 7) ^ ((c >> 3) & 7);
      uint4 v = *reinterpret_cast<const uint4*>(
          sbytes + c * 512 + ((chunk * 16) ^ (m1 << 4)));
      *reinterpret_cast<uint4*>(distT + (size_t)(bcol + c) * BDIM + brow +
                                chunk * 8) = v;
    }
  }
  // dist: lanes 0-31 cover row r's full 512B per instruction; scalar gather
  {
    int chunk = lane & 31, rs = lane >> 5;
#pragma unroll
    for (int i = 0; i < 16; ++i) {
      int r = w * 32 + i * 2 + rs;
      alignas(16) unsigned short buf[8];
#pragma unroll
      for (int j = 0; j < 8; ++j) {
        int c = chunk * 8 + j;
        int m1 = (c & 7) ^ ((c >> 3) & 7);
        buf[j] = *reinterpret_cast<const unsigned short*>(
            sbytes + c * 512 + ((r * 2) ^ (m1 << 4)));
      }
      *reinterpret_cast<uint4*>(dist + (size_t)(brow + r) * BDIM + bcol +
                                chunk * 8) = *reinterpret_cast<const uint4*>(buf);
    }
  }
}

// ---------------- per-row exact top-K-smallest hinge sum (bf16 keys) ------
__global__ __launch_bounds__(256, 4) void select_kernel(
    const unsigned short* __restrict__ dist,
    const unsigned short* __restrict__ distT,
    const float* __restrict__ posv,
    float* __restrict__ rxy, float* __restrict__ ryx) {
  int lane = threadIdx.x & 63, w = threadIdx.x >> 6;
  int r = blockIdx.x * 4 + w;           // 0..8191
  int rr = (r < BDIM) ? r : r - BDIM;
  const unsigned short* rowp =
      ((r < BDIM) ? dist : distT) + (size_t)rr * BDIM;
  float pos = posv[rr];

  uint32_t key[64];
  uint32_t kmin = 0xFFFFu, kmax = 0u;
#pragma unroll
  for (int i = 0; i < 8; ++i) {
    int idx0 = i * 512 + lane * 8;
    uint4 v = *reinterpret_cast<const uint4*>(rowp + idx0);
    uint32_t pk[4] = {v.x, v.y, v.z, v.w};
#pragma unroll
    for (int p = 0; p < 4; ++p) {
      uint32_t lo = pk[p] & 0xFFFFu, hi = pk[p] >> 16;
      kmin = min(kmin, min(lo, hi));
      kmax = max(kmax, max(lo, hi));
      int idx = idx0 + p * 2;
      key[i * 8 + p * 2 + 0] = (idx + 0 == rr) ? 0xFFFFu : lo;
      key[i * 8 + p * 2 + 1] = (idx + 1 == rr) ? 0xFFFFu : hi;
    }
  }
#pragma unroll
  for (int off = 32; off > 0; off >>= 1) {
    kmin = min(kmin, (uint32_t)__shfl_xor((int)kmin, off));
    kmax = max(kmax, (uint32_t)__shfl_xor((int)kmax, off));
  }

  uint32_t a = kmin, b = kmax;
  uint32_t T;
  bool found = false;
  while (a < b) {
    uint32_t m = (a + b) >> 1;
    int c = 0;
#pragma unroll
    for (int i = 0; i < 64; ++i) c += __popcll(__ballot(key[i] <= m));
    if (c == KSEL) { T = m; found = true; break; }
    if (c > KSEL) b = m; else a = m + 1;
  }
  if (!found) T = a;

  float Tf = __uint_as_float(T << 16);
  float pm = MARGINF + pos;
  float local = 0.f;
  int cnt_less = 0;
#pragma unroll
  for (int i = 0; i < 64; ++i) {
    uint32_t k = key[i];
    cnt_less += __popcll(__ballot(k < T));
    float d = __uint_as_float(k << 16);
    local += (k < T) ? fmaxf(pm - d, 0.f) : 0.f;
  }
#pragma unroll
  for (int off = 32; off > 0; off >>= 1) local += __shfl_xor(local, off);
  if (lane == 0) {
    float loss = local + (float)(KSEL - cnt_less) * fmaxf(pm - Tf, 0.f);
    if (r < BDIM) rxy[rr] = loss; else ryx[rr] = loss;
  }
}

// ---------------- final reduction ----------------
__global__ void finalize_kernel(const float* __restrict__ rxy,
                                const float* __restrict__ ryx,
                                float* __restrict__ out) {
  const float* src = (blockIdx.x == 0) ? rxy : ryx;
  int tid = threadIdx.x;
  double local = 0.0;
  for (int i = tid; i < BDIM; i += 256) local += (double)src[i];
  int lane = tid & 63, w = tid >> 6;
#pragma unroll
  for (int off = 32; off > 0; off >>= 1) local += __shfl_down(local, off);
  __shared__ double wsd[4];
  if (lane == 0) wsd[w] = local;
  __syncthreads();
  if (tid == 0) {
    double s = wsd[0] + wsd[1] + wsd[2] + wsd[3];
    out[blockIdx.x] = (float)(s / ((double)BDIM * (double)KSEL));
  }
}

// ---------------- launch ----------------
extern "C" void kernel_launch(void* const* d_in, const int* in_sizes, int n_in,
                              void* d_out, int out_size, void* d_ws,
                              size_t ws_size, hipStream_t stream) {
  const float* x = (const float*)d_in[0];
  const float* y = (const float*)d_in[1];
  float* out = (float*)d_out;

  char* ws = (char*)d_ws;
  size_t o = 0;
  auto take = [&](size_t bytes) -> void* {
    void* p = (void*)(ws + o);
    o += (bytes + 255) & ~(size_t)255;
    return p;
  };
  unsigned short* xbf = (unsigned short*)take((size_t)BDIM * DDIM * 2);
  unsigned short* ybf = (unsigned short*)take((size_t)BDIM * DDIM * 2);
  float* xn = (float*)take((size_t)BDIM * 4);
  float* yn = (float*)take((size_t)BDIM * 4);
  float* rxy = (float*)take((size_t)BDIM * 4);
  float* ryx = (float*)take((size_t)BDIM * 4);
  float* posv = (float*)take((size_t)BDIM * 4);
  unsigned short* dist = (unsigned short*)take((size_t)BDIM * BDIM * 2);
  unsigned short* distT = (unsigned short*)take((size_t)BDIM * BDIM * 2);

  prep_kernel<<<BDIM / 4, 256, 0, stream>>>(x, y, xbf, ybf, xn, yn, posv);
  gemm_dist_kernel<<<256, 512, 0, stream>>>(xbf, ybf, xn, yn, dist, distT);
  select_kernel<<<2 * BDIM / 4, 256, 0, stream>>>(dist, distT, posv, rxy, ryx);
  finalize_kernel<<<2, 256, 0, stream>>>(rxy, ryx, out);
}

// Round 10
// 147.687 us; speedup vs baseline: 1.1602x; 1.0032x over previous
//
#include <hip/hip_runtime.h>
#include <hip/hip_bf16.h>
#include <stdint.h>

#define BDIM 4096
#define DDIM 1024
#define KSEL 1024
#define MARGINF 0.5f
#define EPSF 1e-6f
#define NT 16  // K-tiles of 64

typedef __attribute__((ext_vector_type(8))) short short8v;
typedef __attribute__((ext_vector_type(4))) float float4v;

// ---------------- helpers ----------------

__device__ __forceinline__ unsigned short f2bf(float f) {
  uint32_t u = __float_as_uint(f);
  uint32_t r = (u + 0x7FFFu + ((u >> 16) & 1u)) >> 16;
  return (unsigned short)r;
}

__device__ __forceinline__ float bf2f(unsigned short u) {
  return __uint_as_float((uint32_t)u << 16);
}

__device__ __forceinline__ void gload_lds16(const void* g, void* l) {
  __builtin_amdgcn_global_load_lds(
      (const __attribute__((address_space(1))) void*)g,
      (__attribute__((address_space(3))) void*)l, 16, 0, 0);
}

// ---------------- prep: fp32 -> bf16, norms, and exact-pipeline posv ------
__global__ __launch_bounds__(256) void prep_kernel(
    const float* __restrict__ x, const float* __restrict__ y,
    unsigned short* __restrict__ xbf, unsigned short* __restrict__ ybf,
    float* __restrict__ xn, float* __restrict__ yn,
    float* __restrict__ posv) {
  int wv = threadIdx.x >> 6, lane = threadIdx.x & 63;
  int row = blockIdx.x * 4 + wv;  // 0..4095
  const float* xp = x + (size_t)row * DDIM;
  const float* yp = y + (size_t)row * DDIM;
  unsigned short* xo = xbf + (size_t)row * DDIM;
  unsigned short* yo = ybf + (size_t)row * DDIM;
  float sxx = 0.f, syy = 0.f, sxy = 0.f;
#pragma unroll
  for (int it = 0; it < 4; ++it) {
    int k = it * 256 + lane * 4;
    float4 xv = *reinterpret_cast<const float4*>(xp + k);
    float4 yv = *reinterpret_cast<const float4*>(yp + k);
    xv.x += EPSF; xv.y += EPSF; xv.z += EPSF; xv.w += EPSF;
    sxx += xv.x * xv.x + xv.y * xv.y + xv.z * xv.z + xv.w * xv.w;
    syy += yv.x * yv.x + yv.y * yv.y + yv.z * yv.z + yv.w * yv.w;
    ushort4 xq, yq;
    xq.x = f2bf(xv.x); xq.y = f2bf(xv.y); xq.z = f2bf(xv.z); xq.w = f2bf(xv.w);
    yq.x = f2bf(yv.x); yq.y = f2bf(yv.y); yq.z = f2bf(yv.z); yq.w = f2bf(yv.w);
    sxy += bf2f(xq.x) * bf2f(yq.x) + bf2f(xq.y) * bf2f(yq.y) +
           bf2f(xq.z) * bf2f(yq.z) + bf2f(xq.w) * bf2f(yq.w);
    *reinterpret_cast<ushort4*>(xo + k) = xq;
    *reinterpret_cast<ushort4*>(yo + k) = yq;
  }
#pragma unroll
  for (int off = 32; off > 0; off >>= 1) {
    sxx += __shfl_down(sxx, off);
    syy += __shfl_down(syy, off);
    sxy += __shfl_down(sxy, off);
  }
  if (lane == 0) {
    xn[row] = sxx;
    yn[row] = syy;
    posv[row] = sqrtf(fmaxf(sxx + syy - 2.f * sxy, 0.f));
  }
}

// ---------------- GEMM: 256x256, BK=64, 8 waves, m201 8-phase pipeline ----
// 8 phases per 2 K-tiles (even tile -> buf0, odd -> buf1). Per phase:
// {ds-read frags, STAGE one half-tile, [wait], bar, lgkmcnt(0)+fence,
//  setprio(1), 16 MFMA, setprio(0), bar}. Stage order per iteration:
// A1(t+1)@p0 A0(t+2)@p1 B0(t+2)@p2 B1(t+2)@p3 A1(t+2)@p4 A0(t+3)@p5
// B0(t+3)@p6 B1(t+3)@p7. Counted waits: vmcnt(6) at p3 and p7 only
// (ledger: 14 loads in flight, leave 6 = last 3 halves). Last iter:
// vmcnt(0)@p3. Every slot restaged >=1 full phase after its last ds-read.

#define VMW(N) asm volatile("s_waitcnt vmcnt(" #N ")" ::: "memory")
#define LGKM0()                                         \
  asm volatile("s_waitcnt lgkmcnt(0)" ::: "memory");    \
  __builtin_amdgcn_sched_barrier(0)
#define LGKM8() asm volatile("s_waitcnt lgkmcnt(8)" ::: "memory")

#define STAGE(srcbase, ldsb)                                          \
  {                                                                   \
    _Pragma("unroll") for (int c = 0; c < 2; ++c) {                   \
      int L = tid + c * 512;                                          \
      int row_ = L >> 3;                                              \
      int ch_ = (L & 7) ^ (row_ & 7);                                 \
      gload_lds16((srcbase) + (size_t)row_ * DDIM + ch_ * 8,          \
                  (ldsb) + ((w * 64 + c * 512) << 3));                \
    }                                                                 \
  }

#define LOADA(dst, qm, d)                                             \
  {                                                                   \
    _Pragma("unroll") for (int mm = 0; mm < 4; ++mm)                  \
        _Pragma("unroll") for (int ks = 0; ks < 2; ++ks) {            \
      int rh = wr * 64 + mm * 16 + (lane & 15);                       \
      int ch = (ks * 4 + (lane >> 4)) ^ (rh & 7);                     \
      dst[mm][ks] = *reinterpret_cast<const short8v*>(                \
          smem + ((d) * 2 + (qm)) * 8192 + rh * 64 + ch * 8);         \
    }                                                                 \
  }

#define LOADB(dst, qn, d)                                             \
  {                                                                   \
    _Pragma("unroll") for (int nn = 0; nn < 2; ++nn)                  \
        _Pragma("unroll") for (int ks = 0; ks < 2; ++ks) {            \
      int rh = wc * 32 + nn * 16 + (lane & 15);                       \
      int ch = (ks * 4 + (lane >> 4)) ^ (rh & 7);                     \
      dst[nn][ks] = *reinterpret_cast<const short8v*>(                \
          smem + 32768 + ((d) * 2 + (qn)) * 8192 + rh * 64 + ch * 8); \
    }                                                                 \
  }

#define MFMAQ(qm, qn, bsrc)                                           \
  {                                                                   \
    __builtin_amdgcn_s_setprio(1);                                    \
    _Pragma("unroll") for (int mm = 0; mm < 4; ++mm)                  \
        _Pragma("unroll") for (int nn = 0; nn < 2; ++nn)              \
            _Pragma("unroll") for (int ks = 0; ks < 2; ++ks) {        \
      acc[qm][qn][mm][nn] = __builtin_amdgcn_mfma_f32_16x16x32_bf16(  \
          a[mm][ks], bsrc[nn][ks], acc[qm][qn][mm][nn], 0, 0, 0);     \
    }                                                                 \
    __builtin_amdgcn_s_setprio(0);                                    \
  }

#define BAR() __builtin_amdgcn_s_barrier()

__global__ __launch_bounds__(512, 2) void gemm_dist_kernel(
    const unsigned short* __restrict__ Xb, const unsigned short* __restrict__ Yb,
    const float* __restrict__ xn, const float* __restrict__ yn,
    unsigned short* __restrict__ dist, unsigned short* __restrict__ distT) {
  __shared__ unsigned short smem[65536];  // 128 KB

  int tid = threadIdx.x;
  int lane = tid & 63, w = tid >> 6;
  int wr = w >> 2, wc = w & 3;
  // XCD-aware swizzle over 256 blocks (16x16 tile grid), bijective
  int wg = blockIdx.x;
  int swz = (wg & 7) * 32 + (wg >> 3);
  int brow = (swz >> 4) * 256, bcol = (swz & 15) * 256;

  float4v acc[2][2][4][2];
#pragma unroll
  for (int i = 0; i < 2; ++i)
#pragma unroll
    for (int j = 0; j < 2; ++j)
#pragma unroll
      for (int m = 0; m < 4; ++m)
#pragma unroll
        for (int n = 0; n < 2; ++n) acc[i][j][m][n] = (float4v){0.f, 0.f, 0.f, 0.f};

  short8v a[4][2], b0[2][2], b1[2][2];

  // slot helpers (ushort offsets): A(buf,h) = (buf*2+h)*8192; B: +32768
  unsigned short* As00 = smem;
  unsigned short* As01 = smem + 8192;
  unsigned short* As10 = smem + 16384;
  unsigned short* As11 = smem + 24576;
  unsigned short* Bs00 = smem + 32768;
  unsigned short* Bs01 = smem + 40960;
  unsigned short* Bs10 = smem + 49152;
  unsigned short* Bs11 = smem + 57344;

  // prologue: stage 7 half-tiles (tile0: A0,B0,B1,A1; tile1: A0,B0,B1)
  STAGE(Xb + (size_t)brow * DDIM, As00);
  STAGE(Yb + (size_t)bcol * DDIM, Bs00);
  STAGE(Yb + (size_t)(bcol + 128) * DDIM, Bs01);
  STAGE(Xb + (size_t)(brow + 128) * DDIM, As01);
  STAGE(Xb + (size_t)brow * DDIM + 64, As10);
  STAGE(Yb + (size_t)bcol * DDIM + 64, Bs10);
  STAGE(Yb + (size_t)(bcol + 128) * DDIM + 64, Bs11);
  VMW(6);  // drain tile 0 (4 halves); leave tile1's 3 halves in flight
  BAR();

  for (int it = 0; it < NT / 2; ++it) {
    int t = 2 * it;
    bool more = (it < NT / 2 - 1);
    const unsigned short* x2 = Xb + (size_t)brow * DDIM + (t + 2) * 64;
    const unsigned short* y2 = Yb + (size_t)bcol * DDIM + (t + 2) * 64;
    const unsigned short* x3 = Xb + (size_t)brow * DDIM + (t + 3) * 64;
    const unsigned short* y3 = Yb + (size_t)bcol * DDIM + (t + 3) * 64;

    // ---- phase 0: (t, Q00) ---- stage A1(t+1)
    LOADA(a, 0, 0);
    LOADB(b0, 0, 0);
    STAGE(Xb + (size_t)(brow + 128) * DDIM + (t + 1) * 64, As11);
    LGKM8();
    BAR();
    LGKM0();
    MFMAQ(0, 0, b0);
    BAR();
    // ---- phase 1: (t, Q01) ---- stage A0(t+2)
    LOADB(b1, 1, 0);
    if (more) STAGE(x2, As00);
    BAR();
    LGKM0();
    MFMAQ(0, 1, b1);
    BAR();
    // ---- phase 2: (t, Q10) ---- stage B0(t+2)
    LOADA(a, 1, 0);
    if (more) STAGE(y2, Bs00);
    BAR();
    LGKM0();
    MFMAQ(1, 0, b0);
    BAR();
    // ---- phase 3: (t, Q11) ---- stage B1(t+2); WAIT
    if (more) {
      STAGE(y2 + (size_t)128 * DDIM, Bs01);
      VMW(6);
    } else {
      VMW(0);
    }
    BAR();
    __builtin_amdgcn_sched_barrier(0);
    MFMAQ(1, 1, b1);
    BAR();
    // ---- phase 4: (t+1, Q00) ---- stage A1(t+2)
    LOADA(a, 0, 1);
    LOADB(b0, 0, 1);
    if (more) STAGE(x2 + (size_t)128 * DDIM, As01);
    LGKM8();
    BAR();
    LGKM0();
    MFMAQ(0, 0, b0);
    BAR();
    // ---- phase 5: (t+1, Q01) ---- stage A0(t+3)
    LOADB(b1, 1, 1);
    if (more) STAGE(x3, As10);
    BAR();
    LGKM0();
    MFMAQ(0, 1, b1);
    BAR();
    // ---- phase 6: (t+1, Q10) ---- stage B0(t+3)
    LOADA(a, 1, 1);
    if (more) STAGE(y3, Bs10);
    BAR();
    LGKM0();
    MFMAQ(1, 0, b0);
    BAR();
    // ---- phase 7: (t+1, Q11) ---- stage B1(t+3); WAIT
    if (more) {
      STAGE(y3 + (size_t)128 * DDIM, Bs11);
      VMW(6);
    }
    BAR();
    __builtin_amdgcn_sched_barrier(0);
    MFMAQ(1, 1, b1);
    BAR();
  }

  // ---- epilogue (round-8-proven) ----
  // Column-major LDS tile: byte(c,r) = c*512 + ((2r) ^ (m1(c)<<4)),
  // m1(c) = (c&7)^((c>>3)&7).
  char* sbytes = reinterpret_cast<char*>(smem);
#pragma unroll
  for (int qm = 0; qm < 2; ++qm) {
#pragma unroll
    for (int qn = 0; qn < 2; ++qn) {
#pragma unroll
      for (int mm = 0; mm < 4; ++mm) {
#pragma unroll
        for (int nn = 0; nn < 2; ++nn) {
          int r0 = qm * 128 + wr * 64 + mm * 16 + (lane >> 4) * 4;
          int c = qn * 128 + wc * 32 + nn * 16 + (lane & 15);
          float yv = yn[bcol + c];
          ushort4 st;
          unsigned short* sp = reinterpret_cast<unsigned short*>(&st);
#pragma unroll
          for (int j = 0; j < 4; ++j) {
            float sq = xn[brow + r0 + j] + yv - 2.0f * acc[qm][qn][mm][nn][j];
            sp[j] = f2bf(sqrtf(fmaxf(sq, 0.f)));
          }
          int m1 = (c & 7) ^ ((c >> 3) & 7);
          *reinterpret_cast<uint2*>(sbytes + c * 512 +
                                    ((r0 * 2) ^ (m1 << 4))) =
              *reinterpret_cast<uint2*>(&st);
        }
      }
    }
  }
  __syncthreads();
  // distT: lanes 0-31 cover column c's full 512B per instruction
  {
    int chunk = lane & 31, cs = lane >> 5;
#pragma unroll
    for (int i = 0; i < 16; ++i) {
      int c = w * 32 + i * 2 + cs;
      int m1 = (c & 7) ^ ((c >> 3) & 7);
      uint4 v = *reinterpret_cast<const uint4*>(
          sbytes + c * 512 + ((chunk * 16) ^ (m1 << 4)));
      *reinterpret_cast<uint4*>(distT + (size_t)(bcol + c) * BDIM + brow +
                                chunk * 8) = v;
    }
  }
  // dist: lanes 0-31 cover row r's full 512B per instruction; scalar gather
  {
    int chunk = lane & 31, rs = lane >> 5;
#pragma unroll
    for (int i = 0; i < 16; ++i) {
      int r = w * 32 + i * 2 + rs;
      alignas(16) unsigned short buf[8];
#pragma unroll
      for (int j = 0; j < 8; ++j) {
        int c = chunk * 8 + j;
        int m1 = (c & 7) ^ ((c >> 3) & 7);
        buf[j] = *reinterpret_cast<const unsigned short*>(
            sbytes + c * 512 + ((r * 2) ^ (m1 << 4)));
      }
      *reinterpret_cast<uint4*>(dist + (size_t)(brow + r) * BDIM + bcol +
                                chunk * 8) = *reinterpret_cast<const uint4*>(buf);
    }
  }
}

// ---------------- per-row exact top-K-smallest hinge sum (bf16 keys) ------
__global__ __launch_bounds__(256, 4) void select_kernel(
    const unsigned short* __restrict__ dist,
    const unsigned short* __restrict__ distT,
    const float* __restrict__ posv,
    float* __restrict__ rxy, float* __restrict__ ryx) {
  int lane = threadIdx.x & 63, w = threadIdx.x >> 6;
  int r = blockIdx.x * 4 + w;           // 0..8191
  int rr = (r < BDIM) ? r : r - BDIM;
  const unsigned short* rowp =
      ((r < BDIM) ? dist : distT) + (size_t)rr * BDIM;
  float pos = posv[rr];

  uint32_t key[64];
  uint32_t kmin = 0xFFFFu, kmax = 0u;
#pragma unroll
  for (int i = 0; i < 8; ++i) {
    int idx0 = i * 512 + lane * 8;
    uint4 v = *reinterpret_cast<const uint4*>(rowp + idx0);
    uint32_t pk[4] = {v.x, v.y, v.z, v.w};
#pragma unroll
    for (int p = 0; p < 4; ++p) {
      uint32_t lo = pk[p] & 0xFFFFu, hi = pk[p] >> 16;
      kmin = min(kmin, min(lo, hi));
      kmax = max(kmax, max(lo, hi));
      int idx = idx0 + p * 2;
      key[i * 8 + p * 2 + 0] = (idx + 0 == rr) ? 0xFFFFu : lo;
      key[i * 8 + p * 2 + 1] = (idx + 1 == rr) ? 0xFFFFu : hi;
    }
  }
#pragma unroll
  for (int off = 32; off > 0; off >>= 1) {
    kmin = min(kmin, (uint32_t)__shfl_xor((int)kmin, off));
    kmax = max(kmax, (uint32_t)__shfl_xor((int)kmax, off));
  }

  uint32_t a = kmin, b = kmax;
  uint32_t T;
  bool found = false;
  while (a < b) {
    uint32_t m = (a + b) >> 1;
    int c = 0;
#pragma unroll
    for (int i = 0; i < 64; ++i) c += __popcll(__ballot(key[i] <= m));
    if (c == KSEL) { T = m; found = true; break; }
    if (c > KSEL) b = m; else a = m + 1;
  }
  if (!found) T = a;

  float Tf = __uint_as_float(T << 16);
  float pm = MARGINF + pos;
  float local = 0.f;
  int cnt_less = 0;
#pragma unroll
  for (int i = 0; i < 64; ++i) {
    uint32_t k = key[i];
    cnt_less += __popcll(__ballot(k < T));
    float d = __uint_as_float(k << 16);
    local += (k < T) ? fmaxf(pm - d, 0.f) : 0.f;
  }
#pragma unroll
  for (int off = 32; off > 0; off >>= 1) local += __shfl_xor(local, off);
  if (lane == 0) {
    float loss = local + (float)(KSEL - cnt_less) * fmaxf(pm - Tf, 0.f);
    if (r < BDIM) rxy[rr] = loss; else ryx[rr] = loss;
  }
}

// ---------------- final reduction ----------------
__global__ void finalize_kernel(const float* __restrict__ rxy,
                                const float* __restrict__ ryx,
                                float* __restrict__ out) {
  const float* src = (blockIdx.x == 0) ? rxy : ryx;
  int tid = threadIdx.x;
  double local = 0.0;
  for (int i = tid; i < BDIM; i += 256) local += (double)src[i];
  int lane = tid & 63, w = tid >> 6;
#pragma unroll
  for (int off = 32; off > 0; off >>= 1) local += __shfl_down(local, off);
  __shared__ double wsd[4];
  if (lane == 0) wsd[w] = local;
  __syncthreads();
  if (tid == 0) {
    double s = wsd[0] + wsd[1] + wsd[2] + wsd[3];
    out[blockIdx.x] = (float)(s / ((double)BDIM * (double)KSEL));
  }
}

// ---------------- launch ----------------
extern "C" void kernel_launch(void* const* d_in, const int* in_sizes, int n_in,
                              void* d_out, int out_size, void* d_ws,
                              size_t ws_size, hipStream_t stream) {
  const float* x = (const float*)d_in[0];
  const float* y = (const float*)d_in[1];
  float* out = (float*)d_out;

  char* ws = (char*)d_ws;
  size_t o = 0;
  auto take = [&](size_t bytes) -> void* {
    void* p = (void*)(ws + o);
    o += (bytes + 255) & ~(size_t)255;
    return p;
  };
  unsigned short* xbf = (unsigned short*)take((size_t)BDIM * DDIM * 2);
  unsigned short* ybf = (unsigned short*)take((size_t)BDIM * DDIM * 2);
  float* xn = (float*)take((size_t)BDIM * 4);
  float* yn = (float*)take((size_t)BDIM * 4);
  float* rxy = (float*)take((size_t)BDIM * 4);
  float* ryx = (float*)take((size_t)BDIM * 4);
  float* posv = (float*)take((size_t)BDIM * 4);
  unsigned short* dist = (unsigned short*)take((size_t)BDIM * BDIM * 2);
  unsigned short* distT = (unsigned short*)take((size_t)BDIM * BDIM * 2);

  prep_kernel<<<BDIM / 4, 256, 0, stream>>>(x, y, xbf, ybf, xn, yn, posv);
  gemm_dist_kernel<<<256, 512, 0, stream>>>(xbf, ybf, xn, yn, dist, distT);
  select_kernel<<<2 * BDIM / 4, 256, 0, stream>>>(dist, distT, posv, rxy, ryx);
  finalize_kernel<<<2, 256, 0, stream>>>(rxy, ryx, out);
}